// Round 4
// baseline (117.744 us; speedup 1.0000x reference)
//
#include <hip/hip_runtime.h>

#define NN 8192
#define KK 512
#define INVT 14.285714285714286f   /* 1/0.07 */
#define K2E 20.60992915555662f     /* (1/0.07) * log2(e) */
#define EPSF 1e-6f

#define BM 256
#define BN 64
#define CSPLIT 8
#define COLS_PER_BLOCK (NN / CSPLIT) /* 1024 */
#define NTILES (COLS_PER_BLOCK / BN) /* 16 */

typedef short bf16x8 __attribute__((ext_vector_type(8)));
typedef float f32x4 __attribute__((ext_vector_type(4)));

__device__ __forceinline__ unsigned short f2bf(float f) {
  unsigned int u = __float_as_uint(f);
  u = u + 0x7FFFu + ((u >> 16) & 1u);
  return (unsigned short)(u >> 16);
}

__device__ __forceinline__ void load_lds16(const void* g, void* l) {
  __builtin_amdgcn_global_load_lds(
      (const __attribute__((address_space(1))) unsigned int*)g,
      (__attribute__((address_space(3))) unsigned int*)l, 16, 0, 0);
}

// Kernel 1: fp32 -> bf16 conversion of features + per-class counts.
__global__ void prep_kernel(const float* __restrict__ feats,
                            const int* __restrict__ labels,
                            unsigned short* __restrict__ fb,
                            int* __restrict__ cnt) {
  int tid = blockIdx.x * 256 + threadIdx.x;  // 524288 threads, 8 elems each
  const float4* src = (const float4*)feats + (size_t)tid * 2;
  float4 a = src[0];
  float4 b = src[1];
  bf16x8 o;
  o[0] = (short)f2bf(a.x); o[1] = (short)f2bf(a.y);
  o[2] = (short)f2bf(a.z); o[3] = (short)f2bf(a.w);
  o[4] = (short)f2bf(b.x); o[5] = (short)f2bf(b.y);
  o[6] = (short)f2bf(b.z); o[7] = (short)f2bf(b.w);
  *(bf16x8*)(fb + (size_t)tid * 8) = o;
  if (tid < NN) atomicAdd(&cnt[labels[tid]], 1);
}

// Kernel 2: fused sim = F F^T tile GEMM + exp/mask row-partial accumulation.
// 4 waves/block, 64 rows/wave (4 A row-frags fully in registers, 256 VGPR):
// each 1KB B ds_read feeds 4 MFMAs -> LDS read traffic halved vs round 3.
// Double-buffered B tile (2x64KB LDS, 1 block/CU): stage t+1 overlaps compute t.
__global__ __launch_bounds__(256, 1) void
scl_main_kernel(const unsigned short* __restrict__ fb,
                const int* __restrict__ labels,
                float* __restrict__ Sarr, float* __restrict__ Parr) {
  __shared__ unsigned short lds[2][BN * KK];  // 128 KB double buffer

  const int bid = blockIdx.x;
  const int rowTile = bid / CSPLIT;   // 0..31
  const int colChunk = bid % CSPLIT;  // 0..7  (== XCD id for default dispatch)
  const bool diagBlk = ((rowTile >> 2) == colChunk);
  const int tid = threadIdx.x;
  const int w = tid >> 6;
  const int l = tid & 63;
  const int lo = l & 15;  // A-row / B-col / C-col lane index
  const int g = l >> 4;   // k-group (operands) / row-group (C)

  const int row0 = rowTile * BM + w * 64;
  const int colbase0 = colChunk * COLS_PER_BLOCK;

// Stage 64 cols x 1KB into buf; wave w stages cols w*16..w*16+15.
// LDS dest linear (lane*16); global source inverse-XOR-swizzled so the
// swizzled ds_read spreads the stride-1024B tile across banks.
#define STAGE(buf, colbase)                                                    \
  {                                                                            \
    _Pragma("unroll") for (int j = 0; j < 16; ++j) {                           \
      const int col = w * 16 + j; /* wave-uniform */                           \
      const int kc = (l & 56) | ((l ^ col) & 7);                               \
      const unsigned short* src = fb + (size_t)((colbase) + col) * KK + kc * 8;\
      load_lds16((const void*)src, (void*)&lds[buf][col * KK]);                \
    }                                                                          \
  }

  // Issue tile-0 staging first so A-register loads overlap it.
  STAGE(0, colbase0);

  // A fragments in registers: frag f covers rows row0+f*16 .. +15.
  // Af[f][ks]: row = row0 + f*16 + lo, k = ks*32 + g*8 .. +7
  bf16x8 Af[4][16];
#pragma unroll
  for (int f = 0; f < 4; ++f) {
    const unsigned short* ar = fb + (size_t)(row0 + f * 16 + lo) * KK;
#pragma unroll
    for (int ks = 0; ks < 16; ++ks)
      Af[f][ks] = *(const bf16x8*)(ar + ks * 32 + g * 8);
  }

  int labr[4][4];
#pragma unroll
  for (int f = 0; f < 4; ++f)
#pragma unroll
    for (int r = 0; r < 4; ++r)
      labr[f][r] = labels[row0 + f * 16 + g * 4 + r];

  f32x4 Sac[4], Pac[4];
#pragma unroll
  for (int f = 0; f < 4; ++f) {
    Sac[f] = (f32x4){0.f, 0.f, 0.f, 0.f};
    Pac[f] = (f32x4){0.f, 0.f, 0.f, 0.f};
  }

  __syncthreads();  // tile-0 staged (compiler drains vmcnt here)

  for (int t = 0; t < NTILES; ++t) {
    const int cur = t & 1;
    const int colbase = colbase0 + t * BN;

    // Label loads BEFORE the stage issue: their vmcnt wait is then vmcnt(16),
    // not vmcnt(0) (which would drain the next tile's staging mid-compute).
    int labc[4];
#pragma unroll
    for (int st = 0; st < 4; ++st) labc[st] = labels[colbase + st * 16 + lo];

    if (t + 1 < NTILES) STAGE(cur ^ 1, colbase0 + (t + 1) * BN);

#pragma unroll
    for (int st = 0; st < 4; ++st) {
      const int ct = st * 16 + lo;        // col within tile
      const int colg = colbase + ct;      // global col
      f32x4 acc[4];
#pragma unroll
      for (int f = 0; f < 4; ++f) acc[f] = (f32x4){0.f, 0.f, 0.f, 0.f};
#pragma unroll
      for (int ks = 0; ks < 16; ++ks) {
        const int kc = ks * 4 + g;
        const int phys = (kc & 56) | ((kc ^ ct) & 7);
        bf16x8 Bf = *(const bf16x8*)(&lds[cur][ct * KK + phys * 8]);
#pragma unroll
        for (int f = 0; f < 4; ++f)
          acc[f] = __builtin_amdgcn_mfma_f32_16x16x32_bf16(Af[f][ks], Bf, acc[f], 0, 0, 0);
      }
#pragma unroll
      for (int f = 0; f < 4; ++f) {
#pragma unroll
        for (int r = 0; r < 4; ++r) {
          const float s = acc[f][r];
          const float e = __builtin_amdgcn_exp2f(__builtin_fmaf(s, K2E, -K2E));
          Sac[f][r] += e;
          if (labc[st] == labr[f][r]) Pac[f][r] += s;
          if (diagBlk) {  // subtract self term (always label-matched)
            if (colg == row0 + f * 16 + g * 4 + r) { Sac[f][r] -= e; Pac[f][r] -= s; }
          }
        }
      }
    }
    __syncthreads();  // next-tile staging drained; cur buffer free to overwrite
  }

  // Row-sum reduce across the 16 lanes sharing a row set, one atomic per row.
#pragma unroll
  for (int f = 0; f < 4; ++f) {
#pragma unroll
    for (int r = 0; r < 4; ++r) {
      float s = Sac[f][r], p = Pac[f][r];
#pragma unroll
      for (int m = 1; m < 16; m <<= 1) {
        s += __shfl_xor(s, m, 64);
        p += __shfl_xor(p, m, 64);
      }
      if (lo == 0) {
        atomicAdd(&Sarr[row0 + f * 16 + g * 4 + r], s);
        atomicAdd(&Parr[row0 + f * 16 + g * 4 + r], p);
      }
    }
  }
#undef STAGE
}

// Kernel 3: per-row loss terms + mean reduction into scalar.
// Parr holds raw sum of sims over positives; scale by 1/T here.
__global__ void finish_kernel(const float* __restrict__ Sarr,
                              const float* __restrict__ Parr,
                              const int* __restrict__ labels,
                              const int* __restrict__ cnt,
                              float* __restrict__ out) {
  int i = blockIdx.x * 256 + threadIdx.x;
  float v = 0.f;
  if (i < NN) {
    float C = (float)(cnt[labels[i]] - 1);
    float lp = Parr[i] * INVT - C * (INVT + logf(Sarr[i] + EPSF));
    v = lp / (C + EPSF);
  }
#pragma unroll
  for (int m = 1; m < 64; m <<= 1) v += __shfl_xor(v, m, 64);
  if ((threadIdx.x & 63) == 0) atomicAdd(out, -v * (1.0f / NN));
}

extern "C" void kernel_launch(void* const* d_in, const int* in_sizes, int n_in,
                              void* d_out, int out_size, void* d_ws, size_t ws_size,
                              hipStream_t stream) {
  const float* feats = (const float*)d_in[0];
  const int* labels = (const int*)d_in[1];

  // ws layout: [0, 8MB) bf16 feats; then S (8192 f32), P (8192 f32), cnt (128 i32)
  unsigned short* fb = (unsigned short*)d_ws;
  const size_t FB_BYTES = (size_t)NN * KK * 2;  // 8388608
  float* Sarr = (float*)((char*)d_ws + FB_BYTES);
  float* Parr = Sarr + NN;
  int* cnt = (int*)(Parr + NN);

  hipMemsetAsync((char*)d_ws + FB_BYTES, 0, (size_t)NN * 8 + 512, stream);
  hipMemsetAsync(d_out, 0, sizeof(float), stream);

  prep_kernel<<<dim3((NN * KK / 8) / 256), dim3(256), 0, stream>>>(feats, labels, fb, cnt);
  scl_main_kernel<<<dim3((NN / BM) * CSPLIT), dim3(256), 0, stream>>>(fb, labels, Sarr, Parr);
  finish_kernel<<<dim3(NN / 256), dim3(256), 0, stream>>>(Sarr, Parr, labels, cnt, (float*)d_out);
}

// Round 5
// 117.062 us; speedup vs baseline: 1.0058x; 1.0058x over previous
//
#include <hip/hip_runtime.h>

#define NN 8192
#define KK 512
#define INVT 14.285714285714286f   /* 1/0.07 */
#define K2E 20.60992915555662f     /* (1/0.07) * log2(e) */
#define EPSF 1e-6f

#define BM 256
#define BN 256
#define BK 64
#define NKT (KK / BK) /* 8 K-tiles */

typedef short bf16x8 __attribute__((ext_vector_type(8)));
typedef float f32x4 __attribute__((ext_vector_type(4)));

__device__ __forceinline__ unsigned short f2bf(float f) {
  unsigned int u = __float_as_uint(f);
  u = u + 0x7FFFu + ((u >> 16) & 1u);
  return (unsigned short)(u >> 16);
}

__device__ __forceinline__ void load_lds16(const void* g, void* l) {
  __builtin_amdgcn_global_load_lds(
      (const __attribute__((address_space(1))) unsigned int*)g,
      (__attribute__((address_space(3))) unsigned int*)l, 16, 0, 0);
}

// Kernel 1: fp32 -> bf16 conversion of features + per-class counts.
__global__ void prep_kernel(const float* __restrict__ feats,
                            const int* __restrict__ labels,
                            unsigned short* __restrict__ fb,
                            int* __restrict__ cnt) {
  int tid = blockIdx.x * 256 + threadIdx.x;  // 524288 threads, 8 elems each
  const float4* src = (const float4*)feats + (size_t)tid * 2;
  float4 a = src[0];
  float4 b = src[1];
  bf16x8 o;
  o[0] = (short)f2bf(a.x); o[1] = (short)f2bf(a.y);
  o[2] = (short)f2bf(a.z); o[3] = (short)f2bf(a.w);
  o[4] = (short)f2bf(b.x); o[5] = (short)f2bf(b.y);
  o[6] = (short)f2bf(b.z); o[7] = (short)f2bf(b.w);
  *(bf16x8*)(fb + (size_t)tid * 8) = o;
  if (tid < NN) atomicAdd(&cnt[labels[tid]], 1);
}

// Kernel 2: m201-style 256x256 tile, 8 waves (2M x 4N), wave tile 128x64,
// A+B double-buffered in LDS (BK=64), 4 phases/K-tile, counted-vmcnt gate.
// reads/MFMA = 0.375 -> 1.57 GB total LDS traffic (vs 2.1 GB round 3) with
// only ~200 live VGPRs (acc in AGPR), avoiding round 4's register wall.
__global__ __launch_bounds__(512, 2) void
scl_main_kernel(const unsigned short* __restrict__ fb,
                const int* __restrict__ labels,
                float* __restrict__ Sarr, float* __restrict__ Parr) {
  // 128 KB: buf b at b*32768 shorts; A tile [256 rows][64k] at +0,
  // B tile [256 cols][64k] at +16384 shorts. Rows are 128B = 8 16B-chunks,
  // source-swizzled by involution c ^= (row&7).
  __shared__ __align__(16) unsigned short smem[65536];

  const int bid = blockIdx.x;
  const int xcd = bid & 7, q8 = bid >> 3;      // default dispatch: bid%8 == XCD
  const int colTile = xcd * 4 + (q8 >> 5);     // 32 consecutive blocks per XCD
  const int rowTile = q8 & 31;                 // share one 256KB B-panel (L2)
  const int rowBase = rowTile * BM;
  const int colBase = colTile * BN;

  const int tid = threadIdx.x;
  const int w = tid >> 6, l = tid & 63;
  const int wm = w >> 2, wn = w & 3;           // wave grid 2M x 4N
  const int lo = l & 15, g = l >> 4;

  const int csw = (tid & 7) ^ ((tid >> 3) & 7);  // stage source chunk swizzle

  // Stage issue i: i<4 -> A rows (i&3)*64.., i>=4 -> B cols. One 16B/lane.
  // LDS dest linear (wave-uniform base + lane*16); global source pre-swizzled.
#define STAGE_ONE(b, kt, i)                                                    \
  {                                                                            \
    const int rl = ((i) & 3) * 64 + (tid >> 3);                                \
    const unsigned short* src =                                                \
        fb + (size_t)((((i) < 4) ? rowBase : colBase) + rl) * KK +             \
        (kt) * BK + csw * 8;                                                   \
    load_lds16((const void*)src,                                               \
               (void*)(smem + (b) * 32768 + (((i) < 4) ? 0 : 16384) +          \
                       ((i) & 3) * 4096 + tid * 8));                           \
  }

  // Prologue: stage K-tile 0 into buf 0.
#pragma unroll
  for (int i = 0; i < 8; ++i) STAGE_ONE(0, 0, i);

  f32x4 acc[8][4];
#pragma unroll
  for (int mi = 0; mi < 8; ++mi)
#pragma unroll
    for (int j = 0; j < 4; ++j) acc[mi][j] = (f32x4){0.f, 0.f, 0.f, 0.f};

  // ds_read offsets (shorts). phys chunk = (ks*4+g) ^ (lo&7); row_l&7 == lo&7.
  const int ph0 = (g ^ (lo & 7)) * 8;
  const int ph1 = ph0 ^ 32;
  const int aoff0 = wm * 8192 + lo * 64;           // + cur*32768 + mi*1024 + ph
  const int boff0 = 16384 + wn * 4096 + lo * 64;   // + cur*32768 + j*1024 + ph

  bf16x8 Bq[4][2];

#pragma unroll 2
  for (int kt = 0; kt < NKT; ++kt) {
    const int cur = kt & 1;
    const int aoff = cur * 32768 + aoff0;
    const int boff = cur * 32768 + boff0;
    // Tile gate: own stages for kt retired (issued >=3 phases ago), then
    // cross-wave barrier -> buf[cur] readable, buf[cur^1] free to overwrite.
    asm volatile("s_waitcnt vmcnt(0)" ::: "memory");
    __builtin_amdgcn_s_barrier();

#pragma unroll
    for (int q = 0; q < 4; ++q) {
      // ds_read this phase's A quadrant (rows 2q,2q+1), B once in phase 0.
      bf16x8 Aq[2][2];
#pragma unroll
      for (int m2 = 0; m2 < 2; ++m2) {
        Aq[m2][0] = *(const bf16x8*)(smem + aoff + (2 * q + m2) * 1024 + ph0);
        Aq[m2][1] = *(const bf16x8*)(smem + aoff + (2 * q + m2) * 1024 + ph1);
      }
      if (q == 0) {
#pragma unroll
        for (int j = 0; j < 4; ++j) {
          Bq[j][0] = *(const bf16x8*)(smem + boff + j * 1024 + ph0);
          Bq[j][1] = *(const bf16x8*)(smem + boff + j * 1024 + ph1);
        }
      }
      // Interleave next-tile staging: 2 of 8 loads per phase (T3/T4 pacing).
      if (kt + 1 < NKT) {
        STAGE_ONE(cur ^ 1, kt + 1, 2 * q);
        STAGE_ONE(cur ^ 1, kt + 1, 2 * q + 1);
      }
      __builtin_amdgcn_s_barrier();  // phase alignment (wave role split)
      asm volatile("s_waitcnt lgkmcnt(0)" ::: "memory");
      __builtin_amdgcn_sched_barrier(0);  // rule 18: pin MFMA below the wait
      __builtin_amdgcn_s_setprio(1);
#pragma unroll
      for (int ks = 0; ks < 2; ++ks)
#pragma unroll
        for (int m2 = 0; m2 < 2; ++m2)
#pragma unroll
          for (int j = 0; j < 4; ++j)
            acc[2 * q + m2][j] = __builtin_amdgcn_mfma_f32_16x16x32_bf16(
                Aq[m2][ks], Bq[j][ks], acc[2 * q + m2][j], 0, 0, 0);
      __builtin_amdgcn_s_setprio(0);
    }
  }

  // ---- Epilogue: exp/mask, lane reduce, cross-wave LDS reduce, atomics ----
  int labc[4];
#pragma unroll
  for (int j = 0; j < 4; ++j) labc[j] = labels[colBase + wn * 64 + j * 16 + lo];

  // redS[4][256], redP[4][256] overlay buf0's A region (disjoint from buf1,
  // which holds the last K-tile still being read by lagging waves).
  float* redS = (float*)smem;
  float* redP = redS + 1024;

#pragma unroll
  for (int mi = 0; mi < 8; ++mi) {
    const int rbase = rowBase + wm * 128 + mi * 16 + g * 4;
    int labr[4];
#pragma unroll
    for (int r = 0; r < 4; ++r) labr[r] = labels[rbase + r];
    f32x4 Sv = {0.f, 0.f, 0.f, 0.f}, Pv = {0.f, 0.f, 0.f, 0.f};
#pragma unroll
    for (int j = 0; j < 4; ++j) {
      const int colg = colBase + wn * 64 + j * 16 + lo;
#pragma unroll
      for (int r = 0; r < 4; ++r) {
        const float s = acc[mi][j][r];
        const float e = __builtin_amdgcn_exp2f(__builtin_fmaf(s, K2E, -K2E));
        const bool self = (colg == rbase + r);
        if (!self) {
          Sv[r] += e;
          if (labc[j] == labr[r]) Pv[r] += s;
        }
      }
    }
#pragma unroll
    for (int r = 0; r < 4; ++r) {
      float s = Sv[r], p = Pv[r];
#pragma unroll
      for (int m = 1; m < 16; m <<= 1) {
        s += __shfl_xor(s, m, 64);
        p += __shfl_xor(p, m, 64);
      }
      if (lo == 0) {
        const int rowl = wm * 128 + mi * 16 + g * 4 + r;
        redS[wn * 256 + rowl] = s;
        redP[wn * 256 + rowl] = p;
      }
    }
  }
  __syncthreads();
  if (tid < 256) {
    float S = redS[tid] + redS[256 + tid] + redS[512 + tid] + redS[768 + tid];
    float P = redP[tid] + redP[256 + tid] + redP[512 + tid] + redP[768 + tid];
    atomicAdd(&Sarr[rowBase + tid], S);
    atomicAdd(&Parr[rowBase + tid], P);
  }
#undef STAGE_ONE
}

// Kernel 3: per-row loss terms + mean reduction into scalar.
__global__ void finish_kernel(const float* __restrict__ Sarr,
                              const float* __restrict__ Parr,
                              const int* __restrict__ labels,
                              const int* __restrict__ cnt,
                              float* __restrict__ out) {
  int i = blockIdx.x * 256 + threadIdx.x;
  float v = 0.f;
  if (i < NN) {
    float C = (float)(cnt[labels[i]] - 1);
    float lp = Parr[i] * INVT - C * (INVT + logf(Sarr[i] + EPSF));
    v = lp / (C + EPSF);
  }
#pragma unroll
  for (int m = 1; m < 64; m <<= 1) v += __shfl_xor(v, m, 64);
  if ((threadIdx.x & 63) == 0) atomicAdd(out, -v * (1.0f / NN));
}

extern "C" void kernel_launch(void* const* d_in, const int* in_sizes, int n_in,
                              void* d_out, int out_size, void* d_ws, size_t ws_size,
                              hipStream_t stream) {
  const float* feats = (const float*)d_in[0];
  const int* labels = (const int*)d_in[1];

  // ws layout: [0, 8MB) bf16 feats; then S (8192 f32), P (8192 f32), cnt (128 i32)
  unsigned short* fb = (unsigned short*)d_ws;
  const size_t FB_BYTES = (size_t)NN * KK * 2;  // 8388608
  float* Sarr = (float*)((char*)d_ws + FB_BYTES);
  float* Parr = Sarr + NN;
  int* cnt = (int*)(Parr + NN);

  hipMemsetAsync((char*)d_ws + FB_BYTES, 0, (size_t)NN * 8 + 512, stream);
  hipMemsetAsync(d_out, 0, sizeof(float), stream);

  prep_kernel<<<dim3((NN * KK / 8) / 256), dim3(256), 0, stream>>>(feats, labels, fb, cnt);
  scl_main_kernel<<<dim3((NN / BM) * (NN / BN)), dim3(512), 0, stream>>>(fb, labels, Sarr, Parr);
  finish_kernel<<<dim3(NN / 256), dim3(256), 0, stream>>>(Sarr, Parr, labels, cnt, (float*)d_out);
}